// Round 12
// baseline (143.740 us; speedup 1.0000x reference)
//
#include <hip/hip_runtime.h>
#include <math.h>

typedef float  f32x4   __attribute__((ext_vector_type(4)));
typedef float  f32x16  __attribute__((ext_vector_type(16)));
typedef __bf16 bf16x8  __attribute__((ext_vector_type(8)));
typedef __bf16 bf16x4  __attribute__((ext_vector_type(4)));

#define MFMA16(a, b, c) __builtin_amdgcn_mfma_f32_16x16x32_bf16((a), (b), (c), 0, 0, 0)
#define MFMA32(a, b, c) __builtin_amdgcn_mfma_f32_32x32x16_bf16((a), (b), (c), 0, 0, 0)

// tr-read: 64-bit LDS transpose read (4 bf16), literal offset
#define TRR(dst, a, lit)  asm volatile("ds_read_b64_tr_b16 %0, %1 offset:" lit : "=v"(dst) : "v"(a))
#define TRRM(dst, a, lit) asm volatile("ds_read_b64_tr_b16 %0, %1 offset:" lit : "=v"(dst) : "v"(a) : "memory")
#define SHUF8(a, b) __builtin_shufflevector((a), (b), 0, 1, 2, 3, 4, 5, 6, 7)

typedef __attribute__((address_space(3))) unsigned int lds_u32;
typedef __attribute__((address_space(1))) const unsigned int glb_u32;

__device__ __forceinline__ void gload16(const __bf16* g, char* l) {
    __builtin_amdgcn_global_load_lds((glb_u32*)g, (lds_u32*)l, 16, 0, 0);
}

// problem sizes
static constexpr int BATCH = 4;
static constexpr int CH    = 256;
static constexpr int M_TOT = BATCH * 4096;  // 16384

// qkv softmax pre-scale folded into Q: 0.125 * log2(e)
static constexpr float QSCALE = 0.18033688011112042f;

// workspace layout (bytes, 16-aligned)
static constexpr size_t OFF_WQKV  = 0;                              // 196608 bf16
static constexpr size_t OFF_WOUT  = 196608ull * 2;                  // 65536 bf16
static constexpr size_t OFF_STATS = OFF_WOUT + 65536ull * 2;        // 128 float2
static constexpr size_t OFF_HID   = OFF_STATS + 1024;               // hid / attn_out bf16
static constexpr size_t OFF_Q     = OFF_HID + (size_t)M_TOT * CH * 2;
static constexpr size_t OFF_K     = OFF_Q   + (size_t)M_TOT * CH * 2;
static constexpr size_t OFF_V     = OFF_K   + (size_t)M_TOT * CH * 2;

// ---------------------------------------------------------------------------
// 1) fused: GN stats (blocks 0..127) + weight convert/permute (blocks 128..1151)
// ---------------------------------------------------------------------------
__global__ __launch_bounds__(256) void pre_kernel(const float* __restrict__ x,
                                                  float2* __restrict__ stats,
                                                  const float* __restrict__ wq,
                                                  const float* __restrict__ wo,
                                                  __bf16* __restrict__ wqf,
                                                  __bf16* __restrict__ wof) {
    if (blockIdx.x < 128) {
        int bg = blockIdx.x;  // 0..127
        const float4* p = (const float4*)(x + (size_t)bg * 32768);
        float s = 0.f, ss = 0.f;
        for (int i = threadIdx.x; i < 8192; i += 256) {
            float4 v = p[i];
            s  += (v.x + v.y) + (v.z + v.w);
            ss += v.x * v.x + v.y * v.y + v.z * v.z + v.w * v.w;
        }
#pragma unroll
        for (int d = 32; d > 0; d >>= 1) { s += __shfl_down(s, d); ss += __shfl_down(ss, d); }
        __shared__ float sh[8];
        int w = threadIdx.x >> 6, l = threadIdx.x & 63;
        if (l == 0) { sh[w] = s; sh[4 + w] = ss; }
        __syncthreads();
        if (threadIdx.x == 0) {
            float S = sh[0] + sh[1] + sh[2] + sh[3];
            float SS = sh[4] + sh[5] + sh[6] + sh[7];
            float mean = S * (1.f / 32768.f);
            float var  = SS * (1.f / 32768.f) - mean * mean;
            stats[bg] = make_float2(mean, rsqrtf(var + 1e-5f));
        }
    } else {
        int i = (blockIdx.x - 128) * 256 + threadIdx.x;   // 0 .. 262143
        if (i < 196608) {
            int e = i & 7, l = (i >> 3) & 63, kk = (i >> 9) & 7, jt = i >> 12;  // jt 0..47
            int kidx = kk * 32 + ((l >> 4) << 3) + e;
            int n = jt * 16 + (l & 15);
            wqf[i] = (__bf16)wq[kidx * 768 + n];
        } else {
            int i2 = i - 196608;                  // 0 .. 65535
            int e = i2 & 7, l = (i2 >> 3) & 63, kk = (i2 >> 9) & 7, jt = i2 >> 12;  // jt 0..15
            int kidx = kk * 32 + ((l >> 4) << 3) + e;
            int n = jt * 16 + (l & 15);
            wof[i2] = (__bf16)wo[kidx * 256 + n];
        }
    }
}

// ---------------------------------------------------------------------------
// 2) GN apply + transpose: hid[b][n][c] = gn(x)[b][c][n]  (bf16)
// ---------------------------------------------------------------------------
__global__ __launch_bounds__(256) void gn_apply(const float* __restrict__ x,
                                                const float* __restrict__ gamma,
                                                const float* __restrict__ beta,
                                                const float2* __restrict__ stats,
                                                __bf16* __restrict__ hid) {
    int b  = blockIdx.x >> 6;
    int n0 = (blockIdx.x & 63) << 6;
    int c  = threadIdx.x;
    float2 st = stats[b * 32 + (c >> 3)];
    float gm = gamma[c] * st.y;
    float bt = beta[c] - st.x * gm;
    const float* xp = x + ((size_t)(b * 256 + c)) * 4096 + n0;
    __bf16* hp = hid + ((size_t)(b * 4096 + n0)) * 256 + c;
#pragma unroll
    for (int j4 = 0; j4 < 16; ++j4) {
        float4 v = *(const float4*)(xp + j4 * 4);
        hp[(size_t)(j4 * 4 + 0) * 256] = (__bf16)(v.x * gm + bt);
        hp[(size_t)(j4 * 4 + 1) * 256] = (__bf16)(v.y * gm + bt);
        hp[(size_t)(j4 * 4 + 2) * 256] = (__bf16)(v.z * gm + bt);
        hp[(size_t)(j4 * 4 + 3) * 256] = (__bf16)(v.w * gm + bt);
    }
}

// ---------------------------------------------------------------------------
// 3) QKV GEMM: [16384,256] x [256,768] + bias -> q/k/v [B,H,4096,64] bf16
//    Q pre-scaled by 0.125*log2(e).
// ---------------------------------------------------------------------------
__global__ __launch_bounds__(256) void qkv_gemm(const __bf16* __restrict__ hid,
                                                const __bf16* __restrict__ wf,
                                                const float* __restrict__ bqkv,
                                                __bf16* __restrict__ qb,
                                                __bf16* __restrict__ kb,
                                                __bf16* __restrict__ vb) {
    const int mt = blockIdx.x, nt = blockIdx.y;
    const int tid = threadIdx.x;
    const int w = tid >> 6, l = tid & 63;
    const int lr = l & 15, lh = l >> 4;
    f32x4 acc[4] = {{0.f,0.f,0.f,0.f},{0.f,0.f,0.f,0.f},{0.f,0.f,0.f,0.f},{0.f,0.f,0.f,0.f}};
    const __bf16* ap = hid + (size_t)(mt * 64 + w * 16 + lr) * 256 + lh * 8;
#pragma unroll
    for (int kk = 0; kk < 8; ++kk) {
        bf16x8 a = *(const bf16x8*)(ap + kk * 32);
#pragma unroll
        for (int fj = 0; fj < 4; ++fj) {
            bf16x8 bf = *(const bf16x8*)(wf + (size_t)(((nt * 4 + fj) * 8 + kk) * 64 + l) * 8);
            acc[fj] = MFMA16(a, bf, acc[fj]);
        }
    }
    int mbase = mt * 64 + w * 16 + lh * 4;
#pragma unroll
    for (int fj = 0; fj < 4; ++fj) {
        int j = nt * 64 + fj * 16 + lr;
        int head = j / 192, rem = j % 192;
        int part = rem >> 6, dd = rem & 63;
        float bias = bqkv[j];
        float sc = (part == 0) ? QSCALE : 1.0f;
        __bf16* dst = (part == 0) ? qb : (part == 1) ? kb : vb;
#pragma unroll
        for (int r = 0; r < 4; ++r) {
            int m = mbase + r;
            int b = m >> 12, n = m & 4095;
            dst[((size_t)((b * 4 + head) * 4096 + n)) * 64 + dd] = (__bf16)((acc[fj][r] + bias) * sc);
        }
    }
}

// ---------------------------------------------------------------------------
// 4) Flash attention, swapped-operand, STATIC softmax, 32x32x16 MFMAs.
//    Grid 512 (XCD swizzle), 4 waves x 32 q-rows (128-row supertile).
//    QK^T: S^T[key][q] per kt in {0,1}: 4 chained MFMA32 over d.
//      A = K[kt*32 + (l&31)][d], B = Q[d][q=l&31].
//      D layout: col=q=lane&31, row(key) = (reg&3)+8*(reg>>2)+4*(lane>>5).
//    P B-frag identity: choosing PV key order key(kstep,k) =
//      kt*32 + 16s + 8*(e>>2) + 4h + (e&3)  (kt=kstep>>1, s=kstep&1, k=h*8+e)
//      makes B(kstep)[e] = exp2(S[kt][8s+e]) — pure in-lane, no shuffles.
//    V LDS: 16 tr-units of 512B; unit u = kstep*4 + dt*2 + eh; element
//      (u, ghl, j, ll) holds V[key(kt,s,e=eh*4+j,h=ghl>>1)][dt*32+(ghl&1)*16+ll]
//      staged linearly with permuted global source (G21).
//    lsum via ones-MFMA32 (4/tile).
// ---------------------------------------------------------------------------
__global__ __launch_bounds__(256, 2) void attn_fwd(const __bf16* __restrict__ q,
                                                   const __bf16* __restrict__ k,
                                                   const __bf16* __restrict__ v,
                                                   __bf16* __restrict__ ao) {
    const int id = blockIdx.x;
    const int within = id >> 3;                       // 0..63
    const int bh = ((id & 7) << 1) + (within >> 5);   // XCD (id&7) owns bh pair
    const int q0 = (within & 31) * 128;
    const int tid = threadIdx.x;
    const int wv = tid >> 6, l = tid & 63;
    const int l31 = l & 31, h = l >> 5;

    __shared__ __attribute__((aligned(16))) char smem[32768];  // K dbuf 16K | V dbuf 16K

    const size_t base = (size_t)bh * (4096 * 64);

    // ---- staging addresses (chunk c = wv*64 + l, and +256) ----
    const int c0 = wv * 64 + l;
    const int rK = c0 >> 3, cbK = l & 7;
    const int gk0 = rK * 64 + (cbK ^ (rK & 7)) * 8;        // elements
    const int gk1 = gk0 + 2048;                             // +32 rows
    // V source permutation (see header comment)
    auto vsrc = [](int c) -> int {
        int u = c >> 5, r6 = (c >> 3) & 3, j = (c >> 1) & 3, d8 = c & 1;
        int kstep = u >> 2, dt = (u >> 1) & 1, eh = u & 1;
        int kt = kstep >> 1, s = kstep & 1;
        int hq = r6 >> 1, hh = r6 & 1, e = eh * 4 + j;
        int key = kt * 32 + s * 16 + (e >> 2) * 8 + hq * 4 + (e & 3);
        return key * 64 + dt * 32 + hh * 16 + d8 * 8;
    };
    const int gv0 = vsrc(c0), gv1 = vsrc(c0 + 256);
    const int lw0 = wv * 1024;                              // wave-uniform LDS bases
    const int lw1 = 4096 + wv * 1024;

    const __bf16* kg = k + base;
    const __bf16* vg = v + base;

    // per-lane tr-read bases for V (both buffers)
    const unsigned lanep = (unsigned)((l & 15) * 2 + (l >> 4) * 128);
    const unsigned vA0 = (unsigned)(size_t)(smem + 16384) + lanep;
    const unsigned vA1 = vA0 + 8192u;

    // K A-frag byte offsets (loop-invariant): row = kt*32+l31, d = ks*16+h*8
    int koff[2][4];
#pragma unroll
    for (int kt = 0; kt < 2; ++kt) {
        int row = kt * 32 + l31;
#pragma unroll
        for (int ks = 0; ks < 4; ++ks)
            koff[kt][ks] = row * 128 + ((ks * 32 + h * 16) ^ ((row & 7) << 4));
    }

    // Q B-frags: lane holds Q[q = q0+wv*32+l31][ks*16 + h*8 + e]
    bf16x8 qf[4];
    {
        const __bf16* qp = q + base + (size_t)(q0 + wv * 32 + l31) * 64 + h * 8;
#pragma unroll
        for (int ks = 0; ks < 4; ++ks) qf[ks] = *(const bf16x8*)(qp + ks * 16);
    }
    bf16x8 ones;
#pragma unroll
    for (int e = 0; e < 8; ++e) ones[e] = (__bf16)1.0f;

    f32x16 O0 = (f32x16)0.0f, O1 = (f32x16)0.0f, LS = (f32x16)0.0f;

    // prologue: stage tile 0 into buf 0
    gload16(kg + gk0, smem + lw0);
    gload16(kg + gk1, smem + lw1);
    gload16(vg + gv0, smem + 16384 + lw0);
    gload16(vg + gv1, smem + 16384 + lw1);
    __syncthreads();

    auto body = [&](const char* Kc, unsigned vA, char* kd, char* vd, int tnext) {
        // issue next-tile staging into the other buffer
        if (tnext < 64) {
            const __bf16* kp = kg + (size_t)tnext * 4096;
            const __bf16* vp = vg + (size_t)tnext * 4096;
            gload16(kp + gk0, kd + lw0);
            gload16(kp + gk1, kd + lw1);
            gload16(vp + gv0, vd + lw0);
            gload16(vp + gv1, vd + lw1);
        }

        // ---- S^T = K Q^T (2 x 4 chained MFMA32) ----
        f32x16 S0 = (f32x16)0.0f, S1 = (f32x16)0.0f;
        __builtin_amdgcn_s_setprio(1);
#pragma unroll
        for (int ks = 0; ks < 4; ++ks) {
            bf16x8 ka0 = *(const bf16x8*)(Kc + koff[0][ks]);
            bf16x8 ka1 = *(const bf16x8*)(Kc + koff[1][ks]);
            S0 = MFMA32(ka0, qf[ks], S0);
            S1 = MFMA32(ka1, qf[ks], S1);
        }
        __builtin_amdgcn_s_setprio(0);

        // ---- issue all 16 V tr-reads; latency hides under exp2 ----
        bf16x4 u0, u1, u2, u3, u4, u5, u6, u7, u8, u9, u10, u11, u12, u13, u14, u15;
        TRRM(u0,  vA, "0");    TRR(u1,  vA, "512");
        TRR(u2,  vA, "1024");  TRR(u3,  vA, "1536");
        TRR(u4,  vA, "2048");  TRR(u5,  vA, "2560");
        TRR(u6,  vA, "3072");  TRR(u7,  vA, "3584");
        TRR(u8,  vA, "4096");  TRR(u9,  vA, "4608");
        TRR(u10, vA, "5120");  TRR(u11, vA, "5632");
        TRR(u12, vA, "6144");  TRR(u13, vA, "6656");
        TRR(u14, vA, "7168");  TRR(u15, vA, "7680");

        // ---- static softmax: B(kstep)[e] = bf16(exp2(S[kt][8s+e])) ----
        bf16x8 B0, B1, B2, B3;
#pragma unroll
        for (int e = 0; e < 8; ++e) {
            B0[e] = (__bf16)__builtin_amdgcn_exp2f(S0[e]);
            B1[e] = (__bf16)__builtin_amdgcn_exp2f(S0[8 + e]);
            B2[e] = (__bf16)__builtin_amdgcn_exp2f(S1[e]);
            B3[e] = (__bf16)__builtin_amdgcn_exp2f(S1[8 + e]);
        }

        // ---- single wait + PV cluster (8 PV + 4 ones MFMA32) ----
        asm volatile("s_waitcnt lgkmcnt(0)" ::: "memory");
        __builtin_amdgcn_sched_barrier(0);
        __builtin_amdgcn_s_setprio(1);
        O0 = MFMA32(SHUF8(u0,  u1),  B0, O0);
        O1 = MFMA32(SHUF8(u2,  u3),  B0, O1);
        LS = MFMA32(ones, B0, LS);
        O0 = MFMA32(SHUF8(u4,  u5),  B1, O0);
        O1 = MFMA32(SHUF8(u6,  u7),  B1, O1);
        LS = MFMA32(ones, B1, LS);
        O0 = MFMA32(SHUF8(u8,  u9),  B2, O0);
        O1 = MFMA32(SHUF8(u10, u11), B2, O1);
        LS = MFMA32(ones, B2, LS);
        O0 = MFMA32(SHUF8(u12, u13), B3, O0);
        O1 = MFMA32(SHUF8(u14, u15), B3, O1);
        LS = MFMA32(ones, B3, LS);
        __builtin_amdgcn_s_setprio(0);

        __syncthreads();   // implicit vmcnt(0): staging landed; buf flip safe
    };

    for (int t = 0; t < 64; t += 2) {
        body(smem,        vA0, smem + 8192, smem + 16384 + 8192, t + 1);
        body(smem + 8192, vA1, smem,        smem + 16384,        t + 2);
    }

    // epilogue: every lane holds the full denominator in LS (any reg)
    float inv = 1.0f / LS[0];
    int b = bh >> 2, hd = bh & 3;
    int n = q0 + wv * 32 + l31;
    __bf16* dst = ao + ((size_t)(b * 4096 + n)) * 256 + hd * 64 + h * 4;
#pragma unroll
    for (int dt = 0; dt < 2; ++dt) {
        const f32x16& O = dt ? O1 : O0;
#pragma unroll
        for (int g = 0; g < 4; ++g) {
            bf16x4 pk;
#pragma unroll
            for (int m = 0; m < 4; ++m) pk[m] = (__bf16)(O[g * 4 + m] * inv);
            *(bf16x4*)(dst + dt * 32 + g * 8) = pk;
        }
    }
}

// ---------------------------------------------------------------------------
// 5) out projection + bias + residual + 1/sqrt(2), transposed store [B,C,N]
// ---------------------------------------------------------------------------
__global__ __launch_bounds__(256) void out_gemm(const __bf16* __restrict__ ao,
                                                const __bf16* __restrict__ wf,
                                                const float* __restrict__ bout,
                                                const float* __restrict__ x,
                                                float* __restrict__ out) {
    const int mt = blockIdx.x, nt = blockIdx.y;
    const int tid = threadIdx.x;
    const int w = tid >> 6, l = tid & 63;
    const int lr = l & 15, lh = l >> 4;
    f32x4 acc[4] = {{0.f,0.f,0.f,0.f},{0.f,0.f,0.f,0.f},{0.f,0.f,0.f,0.f},{0.f,0.f,0.f,0.f}};
    const __bf16* ap = ao + (size_t)(mt * 64 + w * 16 + lr) * 256 + lh * 8;
#pragma unroll
    for (int kk = 0; kk < 8; ++kk) {
        bf16x8 a = *(const bf16x8*)(ap + kk * 32);
#pragma unroll
        for (int fj = 0; fj < 4; ++fj) {
            bf16x8 bf = *(const bf16x8*)(wf + (size_t)(((nt * 4 + fj) * 8 + kk) * 64 + l) * 8);
            acc[fj] = MFMA16(a, bf, acc[fj]);
        }
    }
    __shared__ float tile[64][72];
#pragma unroll
    for (int fj = 0; fj < 4; ++fj) {
        float bias = bout[nt * 64 + fj * 16 + lr];
#pragma unroll
        for (int r = 0; r < 4; ++r)
            tile[w * 16 + lh * 4 + r][fj * 16 + lr] = acc[fj][r] + bias;
    }
    __syncthreads();
    int b  = mt >> 6;
    int n0 = (mt & 63) * 64;
    int c0 = nt * 64;
    int cl = tid >> 2, nq = tid & 3;
    size_t gbase = ((size_t)(b * 256 + c0 + cl)) * 4096 + n0 + nq * 16;
#pragma unroll
    for (int i = 0; i < 16; i += 4) {
        float4 xv = *(const float4*)(x + gbase + i);
        float4 ov;
        ov.x = (tile[nq * 16 + i + 0][cl] + xv.x) * 0.70710678118654752f;
        ov.y = (tile[nq * 16 + i + 1][cl] + xv.y) * 0.70710678118654752f;
        ov.z = (tile[nq * 16 + i + 2][cl] + xv.z) * 0.70710678118654752f;
        ov.w = (tile[nq * 16 + i + 3][cl] + xv.w) * 0.70710678118654752f;
        *(float4*)(out + gbase + i) = ov;
    }
}

// ---------------------------------------------------------------------------
extern "C" void kernel_launch(void* const* d_in, const int* in_sizes, int n_in,
                              void* d_out, int out_size, void* d_ws, size_t ws_size,
                              hipStream_t stream) {
    const float* x     = (const float*)d_in[0];
    const float* gamma = (const float*)d_in[1];
    const float* beta  = (const float*)d_in[2];
    const float* W_qkv = (const float*)d_in[3];
    const float* b_qkv = (const float*)d_in[4];
    const float* W_out = (const float*)d_in[5];
    const float* b_out = (const float*)d_in[6];
    float* out = (float*)d_out;
    char* ws = (char*)d_ws;

    __bf16* wqf   = (__bf16*)(ws + OFF_WQKV);
    __bf16* wof   = (__bf16*)(ws + OFF_WOUT);
    float2* stats = (float2*)(ws + OFF_STATS);
    __bf16* hid   = (__bf16*)(ws + OFF_HID);   // hid, then attn_out
    __bf16* qb    = (__bf16*)(ws + OFF_Q);
    __bf16* kb    = (__bf16*)(ws + OFF_K);
    __bf16* vb    = (__bf16*)(ws + OFF_V);

    pre_kernel<<<1152, 256, 0, stream>>>(x, stats, W_qkv, W_out, wqf, wof);
    gn_apply<<<256, 256, 0, stream>>>(x, gamma, beta, stats, hid);
    qkv_gemm<<<dim3(256, 12), 256, 0, stream>>>(hid, wqf, b_qkv, qb, kb, vb);
    attn_fwd<<<512, 256, 0, stream>>>(qb, kb, vb, hid);
    out_gemm<<<dim3(256, 4), 256, 0, stream>>>(hid, wof, b_out, x, out);
}